// Round 6
// baseline (530.649 us; speedup 1.0000x reference)
//
#include <hip/hip_runtime.h>
#include <math.h>

#define BB   64
#define HH   56
#define WWD  56
#define CCH  96
#define SSS  3
#define NTK  49
#define TOKENS (BB*HH*WWD)   // 200704

typedef unsigned short ushort;
typedef short short8 __attribute__((ext_vector_type(8)));
typedef float floatx4 __attribute__((ext_vector_type(4)));

__device__ __forceinline__ ushort f2bf(float f) {
    union { float f; unsigned u; } v; v.f = f;
    unsigned r = v.u + 0x7FFF + ((v.u >> 16) & 1);
    return (ushort)(r >> 16);
}

// fast GELU: x * sigmoid(1.59577*(x + 0.044715 x^3))  (tanh-form, |err|<3e-3)
__device__ __forceinline__ float fgelu(float v) {
    float e = __expf(v * fmaf(0.044715f * v, v, 1.0f) * -1.5957691216057308f);
    return v * __builtin_amdgcn_rcpf(1.0f + e);
}

// bf16 B-fragment arena in ws: frag = 64 lanes x 8 shorts = 512 shorts.
#define WQKV  0
#define WPROJ (54*512)
#define WFC1  (72*512)
#define WFC2  (144*512)
#define NFRAG 216

__global__ __launch_bounds__(256) void wconv(
    const float* __restrict__ qkv_w, const float* __restrict__ proj_w,
    const float* __restrict__ fc1_w, const float* __restrict__ fc2_w,
    ushort* __restrict__ wsb)
{
    int tg = blockIdx.x * 256 + threadIdx.x;
    int frag = tg >> 6, lane = tg & 63, l15 = lane & 15, quad = lane >> 4;
    const float* src; int row, kbase, K;
    if (frag < 54)       { int f = frag;       int ct = f/3,  kt = f%3;  src = qkv_w;  row = ct*16+l15; kbase = kt*32+quad*8; K = 96;  }
    else if (frag < 72)  { int f = frag - 54;  int ct = f/3,  kt = f%3;  src = proj_w; row = ct*16+l15; kbase = kt*32+quad*8; K = 96;  }
    else if (frag < 144) { int f = frag - 72;  int ct = f/3,  kt = f%3;  src = fc1_w;  row = ct*16+l15; kbase = kt*32+quad*8; K = 96;  }
    else                 { int f = frag - 144; int ct = f/12, hc = f%12; src = fc2_w;  row = ct*16+l15; kbase = hc*32+quad*8; K = 384; }
    const float* p = src + (size_t)row * K + kbase;
    ushort tmp[8];
    #pragma unroll
    for (int j = 0; j < 8; ++j) tmp[j] = f2bf(p[j]);
    *(short8*)(wsb + (size_t)frag * 512 + lane * 8) = *(const short8*)tmp;
}

// ---------------------------------------------------------------------------
// Fused Swin block, one block per (batch, window).
// ---------------------------------------------------------------------------
__global__ __launch_bounds__(256) void swin_kernel(
    const float* __restrict__ x,
    const float* __restrict__ n1g, const float* __restrict__ n1b,
    const ushort* __restrict__ wsb,
    const float* __restrict__ qkv_b, const float* __restrict__ rpb,
    const float* __restrict__ proj_b,
    const float* __restrict__ n2g, const float* __restrict__ n2b,
    const float* __restrict__ fc1_b, const float* __restrict__ fc2_b,
    float* __restrict__ out)
{
    __shared__ __align__(16) ushort xa[64][104];  // LN1-out -> q-scratch -> attn-out -> LN2-out
    __shared__ __align__(16) ushort ks[64][104];
    __shared__ __align__(16) ushort vt[96][72];   // 16B-aligned rows
    __shared__ __align__(16) ushort ps[64][72];   // probs; later act chunks [4][16][40]
    __shared__ float rpbs[507];

    const int wgid = blockIdx.x;
    const int b  = wgid >> 6;
    const int wy = (wgid >> 3) & 7;
    const int wx = wgid & 7;
    const int tid  = threadIdx.x;
    const int lane = tid & 63;
    const int wv   = tid >> 6;
    const int l15  = lane & 15;
    const int quad = lane >> 4;
    const int m0   = wv * 16;
    const bool edge = (wy == 7) || (wx == 7);

    for (int i = tid; i < 507; i += 256) rpbs[i] = rpb[i];

    // ---- LN1: two-phase (load all, then reduce); wave owns rows m0..m0+15 ----
    {
        float a0[16], a1[16];
        #pragma unroll
        for (int r16 = 0; r16 < 16; ++r16) {
            int t = m0 + r16;
            if (t < NTK) {
                int yi = t / 7, xi = t - 7 * (t / 7);
                int rr = wy * 7 + yi + SSS; if (rr >= HH)  rr -= HH;
                int cc = wx * 7 + xi + SSS; if (cc >= WWD) cc -= WWD;
                int off = ((b * HH + rr) * WWD + cc) * CCH;
                a0[r16] = x[off + lane];
                a1[r16] = (lane < 32) ? x[off + 64 + lane] : 0.f;
            } else { a0[r16] = 0.f; a1[r16] = 0.f; }
        }
        float g0 = n1g[lane], bb0 = n1b[lane];
        float g1 = (lane < 32) ? n1g[64 + lane] : 0.f;
        float bb1 = (lane < 32) ? n1b[64 + lane] : 0.f;
        #pragma unroll
        for (int r16 = 0; r16 < 16; ++r16) {
            int t = m0 + r16;
            if (t < NTK) {
                float s = a0[r16] + a1[r16];
                float q = a0[r16] * a0[r16] + a1[r16] * a1[r16];
                #pragma unroll
                for (int o = 1; o < 64; o <<= 1) {
                    s += __shfl_xor(s, o);
                    q += __shfl_xor(q, o);
                }
                float mean = s * (1.f / 96.f);
                float var  = q * (1.f / 96.f) - mean * mean;
                float rstd = rsqrtf(var + 1e-5f);
                xa[t][lane] = f2bf((a0[r16] - mean) * rstd * g0 + bb0);
                if (lane < 32) xa[t][64 + lane] = f2bf((a1[r16] - mean) * rstd * g1 + bb1);
            } else {
                xa[t][lane] = 0;
                if (lane < 32) xa[t][64 + lane] = 0;
            }
        }
    }

    // ---- QKV: wave rows x 288 cols; q -> regs, k -> ks, v -> vt ----
    float qreg[6][4];
    for (int ct = 0; ct < 18; ++ct) {
        floatx4 acc = {0.f, 0.f, 0.f, 0.f};
        #pragma unroll
        for (int kt = 0; kt < 3; ++kt) {
            short8 a  = *(const short8*)&xa[m0 + l15][kt * 32 + quad * 8];
            short8 bw = *(const short8*)(wsb + WQKV + (size_t)(ct * 3 + kt) * 512 + lane * 8);
            acc = __builtin_amdgcn_mfma_f32_16x16x32_bf16(a, bw, acc, 0, 0, 0);
        }
        int oc = ct * 16 + l15;
        float bias = qkv_b[oc];
        if (ct < 6) {
            #pragma unroll
            for (int r = 0; r < 4; ++r) qreg[ct][r] = (acc[r] + bias) * 0.17677669529663687f;
        } else if (ct < 12) {
            #pragma unroll
            for (int r = 0; r < 4; ++r) ks[m0 + quad * 4 + r][oc - 96] = f2bf(acc[r] + bias);
        } else {
            #pragma unroll
            for (int r = 0; r < 4; ++r) vt[oc - 192][m0 + quad * 4 + r] = f2bf(acc[r] + bias);
        }
    }
    // q: C-layout -> A-layout via xa scratch (wave-private)
    #pragma unroll
    for (int ct = 0; ct < 6; ++ct)
        #pragma unroll
        for (int r = 0; r < 4; ++r)
            xa[m0 + quad * 4 + r][ct * 16 + l15] = f2bf(qreg[ct][r]);
    short8 aq[3];
    #pragma unroll
    for (int h = 0; h < 3; ++h) aq[h] = *(const short8*)&xa[m0 + l15][h * 32 + quad * 8];
    __syncthreads();   // barrier #1: ks/vt visible

    // ---- per-row geometry ----
    int rowli[4], rowy[4], rowx[4];
    #pragma unroll
    for (int r = 0; r < 4; ++r) {
        int m = m0 + quad * 4 + r;
        int yi = m / 7, xi = m - 7 * yi;
        rowy[r] = yi; rowx[r] = xi;
        int ri = wy * 7 + yi, ci = wx * 7 + xi;
        rowli[r] = (ri < 49 ? 0 : (ri < 53 ? 1 : 2)) * 3 + (ci < 49 ? 0 : (ci < 53 ? 1 : 2));
    }

    // ---- per-head attention ----
    for (int h = 0; h < 3; ++h) {
        const int hb = 32 * h;
        float sc0[4][4];
        #pragma unroll
        for (int ct = 0; ct < 4; ++ct) {
            short8 bk = *(const short8*)&ks[ct * 16 + l15][hb + quad * 8];
            floatx4 acc = {0.f, 0.f, 0.f, 0.f};
            acc = __builtin_amdgcn_mfma_f32_16x16x32_bf16(aq[h], bk, acc, 0, 0, 0);
            #pragma unroll
            for (int r = 0; r < 4; ++r) sc0[ct][r] = acc[r];
        }
        #pragma unroll
        for (int ct = 0; ct < 4; ++ct) {
            int cj = ct * 16 + l15;
            if (cj < NTK) {
                int yj = cj / 7, xj = cj - 7 * yj;
                int lj = 0;
                if (edge) {
                    int rj = wy * 7 + yj, cjc = wx * 7 + xj;
                    lj = (rj < 49 ? 0 : (rj < 53 ? 1 : 2)) * 3 + (cjc < 49 ? 0 : (cjc < 53 ? 1 : 2));
                }
                #pragma unroll
                for (int r = 0; r < 4; ++r) {
                    unsigned ridx = (unsigned)((rowy[r] - yj + 6) * 13 + (rowx[r] - xj + 6));
                    ridx = (ridx < 169u) ? ridx : 0u;   // clamp (pad rows only)
                    float s = sc0[ct][r] + rpbs[ridx * 3 + h];
                    if (edge && rowli[r] != lj) s -= 100.f;
                    sc0[ct][r] = s;
                }
            } else {
                #pragma unroll
                for (int r = 0; r < 4; ++r) sc0[ct][r] = -1e30f;
            }
        }
        #pragma unroll
        for (int r = 0; r < 4; ++r) {
            float mx = fmaxf(fmaxf(sc0[0][r], sc0[1][r]), fmaxf(sc0[2][r], sc0[3][r]));
            #pragma unroll
            for (int o = 1; o < 16; o <<= 1) mx = fmaxf(mx, __shfl_xor(mx, o));
            float sum = 0.f;
            #pragma unroll
            for (int ct = 0; ct < 4; ++ct) { float e = __expf(sc0[ct][r] - mx); sc0[ct][r] = e; sum += e; }
            #pragma unroll
            for (int o = 1; o < 16; o <<= 1) sum += __shfl_xor(sum, o);
            float inv = __builtin_amdgcn_rcpf(sum);
            #pragma unroll
            for (int ct = 0; ct < 4; ++ct)
                ps[m0 + quad * 4 + r][ct * 16 + l15] = f2bf(sc0[ct][r] * inv);
        }
        // PV
        short8 ap0 = *(const short8*)&ps[m0 + l15][quad * 8];
        short8 ap1 = *(const short8*)&ps[m0 + l15][32 + quad * 8];
        #pragma unroll
        for (int nt = 0; nt < 2; ++nt) {
            floatx4 acc = {0.f, 0.f, 0.f, 0.f};
            short8 bv0 = *(const short8*)&vt[hb + nt * 16 + l15][quad * 8];
            short8 bv1 = *(const short8*)&vt[hb + nt * 16 + l15][32 + quad * 8];
            acc = __builtin_amdgcn_mfma_f32_16x16x32_bf16(ap0, bv0, acc, 0, 0, 0);
            acc = __builtin_amdgcn_mfma_f32_16x16x32_bf16(ap1, bv1, acc, 0, 0, 0);
            #pragma unroll
            for (int r = 0; r < 4; ++r)
                xa[m0 + quad * 4 + r][hb + nt * 16 + l15] = f2bf(acc[r]);
        }
    }

    // ---- per-row global offsets (hoisted) + residual prefetch ----
    int gib[4]; bool vld[4];
    #pragma unroll
    for (int r = 0; r < 4; ++r) {
        int m = m0 + quad * 4 + r;
        vld[r] = (m < NTK);
        int rr = wy * 7 + rowy[r] + SSS; if (rr >= HH)  rr -= HH;
        int cc = wx * 7 + rowx[r] + SSS; if (cc >= WWD) cc -= WWD;
        gib[r] = ((b * HH + rr) * WWD + cc) * CCH;
    }
    float xrv[6][4];
    #pragma unroll
    for (int ct = 0; ct < 6; ++ct)
        #pragma unroll
        for (int r = 0; r < 4; ++r)
            xrv[ct][r] = x[gib[r] + ct * 16 + l15];   // safe even for pad rows

    // ---- proj + bias + residual (registers only) ----
    for (int ct = 0; ct < 6; ++ct) {
        floatx4 acc = {0.f, 0.f, 0.f, 0.f};
        #pragma unroll
        for (int kt = 0; kt < 3; ++kt) {
            short8 a  = *(const short8*)&xa[m0 + l15][kt * 32 + quad * 8];
            short8 bw = *(const short8*)(wsb + WPROJ + (size_t)(ct * 3 + kt) * 512 + lane * 8);
            acc = __builtin_amdgcn_mfma_f32_16x16x32_bf16(a, bw, acc, 0, 0, 0);
        }
        float pb = proj_b[ct * 16 + l15];
        #pragma unroll
        for (int r = 0; r < 4; ++r) xrv[ct][r] += acc[r] + pb;
    }

    // ---- LN2 in-register ----
    float gn[6], bn[6];
    #pragma unroll
    for (int ct = 0; ct < 6; ++ct) { gn[ct] = n2g[ct * 16 + l15]; bn[ct] = n2b[ct * 16 + l15]; }
    #pragma unroll
    for (int r = 0; r < 4; ++r) {
        float s = 0.f, q = 0.f;
        #pragma unroll
        for (int ct = 0; ct < 6; ++ct) { s += xrv[ct][r]; q += xrv[ct][r] * xrv[ct][r]; }
        #pragma unroll
        for (int o = 1; o < 16; o <<= 1) { s += __shfl_xor(s, o); q += __shfl_xor(q, o); }
        float mean = s * (1.f / 96.f);
        float var  = q * (1.f / 96.f) - mean * mean;
        float rstd = rsqrtf(var + 1e-5f);
        #pragma unroll
        for (int ct = 0; ct < 6; ++ct)
            xa[m0 + quad * 4 + r][ct * 16 + l15] =
                f2bf((xrv[ct][r] - mean) * rstd * gn[ct] + bn[ct]);
    }

    // ---- MLP: fc1+GELU chunked 32-wide (wave-private act), fc2 accumulate ----
    short8 axn[3];
    #pragma unroll
    for (int kt = 0; kt < 3; ++kt) axn[kt] = *(const short8*)&xa[m0 + l15][kt * 32 + quad * 8];
    ushort (*act)[40] = (ushort(*)[40])((ushort*)ps + wv * 16 * 40);
    floatx4 o2[6];
    #pragma unroll
    for (int ct = 0; ct < 6; ++ct) o2[ct] = (floatx4){0.f, 0.f, 0.f, 0.f};

    for (int hc = 0; hc < 12; ++hc) {
        #pragma unroll
        for (int c2t = 0; c2t < 2; ++c2t) {
            floatx4 acc = {0.f, 0.f, 0.f, 0.f};
            #pragma unroll
            for (int kt = 0; kt < 3; ++kt) {
                short8 bw = *(const short8*)(wsb + WFC1 + (size_t)((hc * 2 + c2t) * 3 + kt) * 512 + lane * 8);
                acc = __builtin_amdgcn_mfma_f32_16x16x32_bf16(axn[kt], bw, acc, 0, 0, 0);
            }
            float b1 = fc1_b[(hc * 2 + c2t) * 16 + l15];
            #pragma unroll
            for (int r = 0; r < 4; ++r)
                act[quad * 4 + r][c2t * 16 + l15] = f2bf(fgelu(acc[r] + b1));
        }
        short8 aact = *(const short8*)&act[l15][quad * 8];
        #pragma unroll
        for (int ct = 0; ct < 6; ++ct) {
            short8 bw = *(const short8*)(wsb + WFC2 + (size_t)(ct * 12 + hc) * 512 + lane * 8);
            o2[ct] = __builtin_amdgcn_mfma_f32_16x16x32_bf16(aact, bw, o2[ct], 0, 0, 0);
        }
    }

    // ---- final: out = xr + fc2 + bias (xr held in registers) ----
    #pragma unroll
    for (int ct = 0; ct < 6; ++ct) {
        float b2 = fc2_b[ct * 16 + l15];
        #pragma unroll
        for (int r = 0; r < 4; ++r)
            if (vld[r]) out[gib[r] + ct * 16 + l15] = xrv[ct][r] + o2[ct][r] + b2;
    }
}

// ---------------------------------------------------------------------------
extern "C" void kernel_launch(void* const* d_in, const int* in_sizes, int n_in,
                              void* d_out, int out_size, void* d_ws, size_t ws_size,
                              hipStream_t stream) {
    const float* x      = (const float*)d_in[0];
    const float* n1g    = (const float*)d_in[1];
    const float* n1b    = (const float*)d_in[2];
    const float* qkv_w  = (const float*)d_in[3];
    const float* qkv_b  = (const float*)d_in[4];
    const float* rpb    = (const float*)d_in[5];
    const float* proj_w = (const float*)d_in[6];
    const float* proj_b = (const float*)d_in[7];
    const float* n2g    = (const float*)d_in[8];
    const float* n2b    = (const float*)d_in[9];
    const float* fc1_w  = (const float*)d_in[10];
    const float* fc1_b  = (const float*)d_in[11];
    const float* fc2_w  = (const float*)d_in[12];
    const float* fc2_b  = (const float*)d_in[13];
    float* out = (float*)d_out;
    ushort* wsb = (ushort*)d_ws;

    wconv<<<NFRAG / 4, 256, 0, stream>>>(qkv_w, proj_w, fc1_w, fc2_w, wsb);
    swin_kernel<<<BB * 64, 256, 0, stream>>>(
        x, n1g, n1b, wsb, qkv_b, rpb, proj_b, n2g, n2b, fc1_b, fc2_b, out);
}

// Round 7
// 515.344 us; speedup vs baseline: 1.0297x; 1.0297x over previous
//
#include <hip/hip_runtime.h>
#include <math.h>

#define BB   64
#define HH   56
#define WWD  56
#define CCH  96
#define SSS  3
#define NTK  49
#define TOKENS (BB*HH*WWD)   // 200704

typedef unsigned short ushort;
typedef short short8 __attribute__((ext_vector_type(8)));
typedef float floatx4 __attribute__((ext_vector_type(4)));

__device__ __forceinline__ ushort f2bf(float f) {
    union { float f; unsigned u; } v; v.f = f;
    unsigned r = v.u + 0x7FFF + ((v.u >> 16) & 1);
    return (ushort)(r >> 16);
}

// fast GELU: x * sigmoid(1.59577*(x + 0.044715 x^3))  (tanh-form, |err|<3e-3)
__device__ __forceinline__ float fgelu(float v) {
    float e = __expf(v * fmaf(0.044715f * v, v, 1.0f) * -1.5957691216057308f);
    return v * __builtin_amdgcn_rcpf(1.0f + e);
}

// bf16 B-fragment arena in ws: frag = 64 lanes x 8 shorts = 512 shorts.
#define WQKV  0
#define WPROJ (54*512)
#define WFC1  (72*512)
#define WFC2  (144*512)
#define NFRAG 216

__global__ __launch_bounds__(256) void wconv(
    const float* __restrict__ qkv_w, const float* __restrict__ proj_w,
    const float* __restrict__ fc1_w, const float* __restrict__ fc2_w,
    ushort* __restrict__ wsb)
{
    int tg = blockIdx.x * 256 + threadIdx.x;
    int frag = tg >> 6, lane = tg & 63, l15 = lane & 15, quad = lane >> 4;
    const float* src; int row, kbase, K;
    if (frag < 54)       { int f = frag;       int ct = f/3,  kt = f%3;  src = qkv_w;  row = ct*16+l15; kbase = kt*32+quad*8; K = 96;  }
    else if (frag < 72)  { int f = frag - 54;  int ct = f/3,  kt = f%3;  src = proj_w; row = ct*16+l15; kbase = kt*32+quad*8; K = 96;  }
    else if (frag < 144) { int f = frag - 72;  int ct = f/3,  kt = f%3;  src = fc1_w;  row = ct*16+l15; kbase = kt*32+quad*8; K = 96;  }
    else                 { int f = frag - 144; int ct = f/12, hc = f%12; src = fc2_w;  row = ct*16+l15; kbase = hc*32+quad*8; K = 384; }
    const float* p = src + (size_t)row * K + kbase;
    ushort tmp[8];
    #pragma unroll
    for (int j = 0; j < 8; ++j) tmp[j] = f2bf(p[j]);
    *(short8*)(wsb + (size_t)frag * 512 + lane * 8) = *(const short8*)tmp;
}

// ---------------------------------------------------------------------------
// Fused Swin block, one block per (batch, window).
// Strides chosen for <=4-way LDS bank conflicts with 8B-aligned rows:
//   xa/ks: 100 (50 dw = 18 mod 32), vt: 68 (34 dw = 2), ps: 88 (44 dw = 12),
//   act: 44 (22 dw).
// ---------------------------------------------------------------------------
__global__ __launch_bounds__(256) void swin_kernel(
    const float* __restrict__ x,
    const float* __restrict__ n1g, const float* __restrict__ n1b,
    const ushort* __restrict__ wsb,
    const float* __restrict__ qkv_b, const float* __restrict__ rpb,
    const float* __restrict__ proj_b,
    const float* __restrict__ n2g, const float* __restrict__ n2b,
    const float* __restrict__ fc1_b, const float* __restrict__ fc2_b,
    float* __restrict__ out)
{
    __shared__ __align__(16) ushort xa[64][100];  // LN1-out -> q-scratch -> attn-out -> LN2-out
    __shared__ __align__(16) ushort ks[64][100];
    __shared__ __align__(16) ushort vt[96][68];
    __shared__ __align__(16) ushort ps[64][88];   // probs; act double-buffer overlay
    __shared__ float rpbs[507];

    const int wgid = blockIdx.x;
    const int b  = wgid >> 6;
    const int wy = (wgid >> 3) & 7;
    const int wx = wgid & 7;
    const int tid  = threadIdx.x;
    const int lane = tid & 63;
    const int wv   = tid >> 6;
    const int l15  = lane & 15;
    const int quad = lane >> 4;
    const int m0   = wv * 16;
    const bool edge = (wy == 7) || (wx == 7);

    for (int i = tid; i < 507; i += 256) rpbs[i] = rpb[i];

    // ---- LN1: float2 lanes (48 active), depth-1 prefetch; wave owns 16 rows ----
    {
        const bool actv = lane < 48;
        const int colb = 2 * lane;
        float2 gg = actv ? *(const float2*)(n1g + colb) : make_float2(0.f, 0.f);
        float2 bb = actv ? *(const float2*)(n1b + colb) : make_float2(0.f, 0.f);
        auto rowoff = [&](int t) -> int {
            int yi = t / 7, xi = t - 7 * yi;
            int rr = wy * 7 + yi + SSS; if (rr >= HH)  rr -= HH;
            int cc = wx * 7 + xi + SSS; if (cc >= WWD) cc -= WWD;
            return ((b * HH + rr) * WWD + cc) * CCH;
        };
        float2 nxt = make_float2(0.f, 0.f);
        if (actv && m0 < NTK) nxt = *(const float2*)(x + rowoff(m0) + colb);
        for (int r16 = 0; r16 < 16; ++r16) {
            int t = m0 + r16;
            float2 cur = nxt;
            nxt = make_float2(0.f, 0.f);
            if (actv && t + 1 < NTK && r16 < 15)
                nxt = *(const float2*)(x + rowoff(t + 1) + colb);
            if (t < NTK) {
                float s = cur.x + cur.y;
                float q = cur.x * cur.x + cur.y * cur.y;
                #pragma unroll
                for (int o = 1; o < 64; o <<= 1) {
                    s += __shfl_xor(s, o);
                    q += __shfl_xor(q, o);
                }
                float mean = s * (1.f / 96.f);
                float var  = q * (1.f / 96.f) - mean * mean;
                float rstd = rsqrtf(var + 1e-5f);
                if (actv) {
                    unsigned pk = (unsigned)f2bf((cur.x - mean) * rstd * gg.x + bb.x)
                                | ((unsigned)f2bf((cur.y - mean) * rstd * gg.y + bb.y) << 16);
                    *(unsigned*)&xa[t][colb] = pk;
                }
            } else {
                if (actv) *(unsigned*)&xa[t][colb] = 0u;
            }
        }
    }

    // ---- QKV: wave rows x 288 cols; q -> regs, k -> ks, v -> vt ----
    short8 ax0 = *(const short8*)&xa[m0 + l15][quad * 8];
    short8 ax1 = *(const short8*)&xa[m0 + l15][32 + quad * 8];
    short8 ax2 = *(const short8*)&xa[m0 + l15][64 + quad * 8];
    float qreg[6][4];
    for (int ct = 0; ct < 18; ++ct) {
        floatx4 acc = {0.f, 0.f, 0.f, 0.f};
        acc = __builtin_amdgcn_mfma_f32_16x16x32_bf16(ax0, *(const short8*)(wsb + WQKV + (size_t)(ct * 3 + 0) * 512 + lane * 8), acc, 0, 0, 0);
        acc = __builtin_amdgcn_mfma_f32_16x16x32_bf16(ax1, *(const short8*)(wsb + WQKV + (size_t)(ct * 3 + 1) * 512 + lane * 8), acc, 0, 0, 0);
        acc = __builtin_amdgcn_mfma_f32_16x16x32_bf16(ax2, *(const short8*)(wsb + WQKV + (size_t)(ct * 3 + 2) * 512 + lane * 8), acc, 0, 0, 0);
        int oc = ct * 16 + l15;
        float bias = qkv_b[oc];
        if (ct < 6) {
            #pragma unroll
            for (int r = 0; r < 4; ++r) qreg[ct][r] = (acc[r] + bias) * 0.17677669529663687f;
        } else if (ct < 12) {
            #pragma unroll
            for (int r = 0; r < 4; ++r) ks[m0 + quad * 4 + r][oc - 96] = f2bf(acc[r] + bias);
        } else {
            #pragma unroll
            for (int r = 0; r < 4; ++r) vt[oc - 192][m0 + quad * 4 + r] = f2bf(acc[r] + bias);
        }
    }
    // q: C-layout -> A-layout via xa scratch (wave-private rows)
    #pragma unroll
    for (int ct = 0; ct < 6; ++ct)
        #pragma unroll
        for (int r = 0; r < 4; ++r)
            xa[m0 + quad * 4 + r][ct * 16 + l15] = f2bf(qreg[ct][r]);
    short8 aq[3];
    #pragma unroll
    for (int h = 0; h < 3; ++h) aq[h] = *(const short8*)&xa[m0 + l15][h * 32 + quad * 8];
    __syncthreads();   // barrier: ks/vt visible

    // ---- per-row geometry + residual prefetch (hidden under 3-head compute) ----
    int rowli[4], rowy[4], rowx[4], gib[4]; bool vld[4];
    #pragma unroll
    for (int r = 0; r < 4; ++r) {
        int m = m0 + quad * 4 + r;
        vld[r] = (m < NTK);
        int yi = m / 7, xi = m - 7 * yi;
        rowy[r] = yi; rowx[r] = xi;
        int ri = wy * 7 + yi, ci = wx * 7 + xi;
        rowli[r] = (ri < 49 ? 0 : (ri < 53 ? 1 : 2)) * 3 + (ci < 49 ? 0 : (ci < 53 ? 1 : 2));
        int rr = wy * 7 + yi + SSS; if (rr >= HH)  rr -= HH;
        int cc = wx * 7 + xi + SSS; if (cc >= WWD) cc -= WWD;
        gib[r] = ((b * HH + rr) * WWD + cc) * CCH;
    }
    float xrv[6][4];
    #pragma unroll
    for (int ct = 0; ct < 6; ++ct)
        #pragma unroll
        for (int r = 0; r < 4; ++r)
            xrv[ct][r] = x[gib[r] + ct * 16 + l15];   // safe even for pad rows

    // ---- per-head attention ----
    for (int h = 0; h < 3; ++h) {
        const int hb = 32 * h;
        float sc0[4][4];
        #pragma unroll
        for (int ct = 0; ct < 4; ++ct) {
            short8 bk = *(const short8*)&ks[ct * 16 + l15][hb + quad * 8];
            floatx4 acc = {0.f, 0.f, 0.f, 0.f};
            acc = __builtin_amdgcn_mfma_f32_16x16x32_bf16(aq[h], bk, acc, 0, 0, 0);
            #pragma unroll
            for (int r = 0; r < 4; ++r) sc0[ct][r] = acc[r];
        }
        #pragma unroll
        for (int ct = 0; ct < 4; ++ct) {
            int cj = ct * 16 + l15;
            if (cj < NTK) {
                int yj = cj / 7, xj = cj - 7 * yj;
                int lj = 0;
                if (edge) {
                    int rj = wy * 7 + yj, cjc = wx * 7 + xj;
                    lj = (rj < 49 ? 0 : (rj < 53 ? 1 : 2)) * 3 + (cjc < 49 ? 0 : (cjc < 53 ? 1 : 2));
                }
                #pragma unroll
                for (int r = 0; r < 4; ++r) {
                    unsigned ridx = (unsigned)((rowy[r] - yj + 6) * 13 + (rowx[r] - xj + 6));
                    ridx = (ridx < 169u) ? ridx : 0u;   // pad rows only
                    float s = sc0[ct][r] + rpbs[ridx * 3 + h];
                    if (edge && rowli[r] != lj) s -= 100.f;
                    sc0[ct][r] = s;
                }
            } else {
                #pragma unroll
                for (int r = 0; r < 4; ++r) sc0[ct][r] = -1e30f;
            }
        }
        #pragma unroll
        for (int r = 0; r < 4; ++r) {
            float mx = fmaxf(fmaxf(sc0[0][r], sc0[1][r]), fmaxf(sc0[2][r], sc0[3][r]));
            #pragma unroll
            for (int o = 1; o < 16; o <<= 1) mx = fmaxf(mx, __shfl_xor(mx, o));
            float sum = 0.f;
            #pragma unroll
            for (int ct = 0; ct < 4; ++ct) { float e = __expf(sc0[ct][r] - mx); sc0[ct][r] = e; sum += e; }
            #pragma unroll
            for (int o = 1; o < 16; o <<= 1) sum += __shfl_xor(sum, o);
            float inv = __builtin_amdgcn_rcpf(sum);
            #pragma unroll
            for (int ct = 0; ct < 4; ++ct)
                ps[m0 + quad * 4 + r][ct * 16 + l15] = f2bf(sc0[ct][r] * inv);
        }
        // PV
        short8 ap0 = *(const short8*)&ps[m0 + l15][quad * 8];
        short8 ap1 = *(const short8*)&ps[m0 + l15][32 + quad * 8];
        #pragma unroll
        for (int nt = 0; nt < 2; ++nt) {
            floatx4 acc = {0.f, 0.f, 0.f, 0.f};
            short8 bv0 = *(const short8*)&vt[hb + nt * 16 + l15][quad * 8];
            short8 bv1 = *(const short8*)&vt[hb + nt * 16 + l15][32 + quad * 8];
            acc = __builtin_amdgcn_mfma_f32_16x16x32_bf16(ap0, bv0, acc, 0, 0, 0);
            acc = __builtin_amdgcn_mfma_f32_16x16x32_bf16(ap1, bv1, acc, 0, 0, 0);
            #pragma unroll
            for (int r = 0; r < 4; ++r)
                xa[m0 + quad * 4 + r][hb + nt * 16 + l15] = f2bf(acc[r]);
        }
    }

    // ---- proj + bias + residual (registers only) ----
    short8 ao0 = *(const short8*)&xa[m0 + l15][quad * 8];
    short8 ao1 = *(const short8*)&xa[m0 + l15][32 + quad * 8];
    short8 ao2 = *(const short8*)&xa[m0 + l15][64 + quad * 8];
    for (int ct = 0; ct < 6; ++ct) {
        floatx4 acc = {0.f, 0.f, 0.f, 0.f};
        acc = __builtin_amdgcn_mfma_f32_16x16x32_bf16(ao0, *(const short8*)(wsb + WPROJ + (size_t)(ct * 3 + 0) * 512 + lane * 8), acc, 0, 0, 0);
        acc = __builtin_amdgcn_mfma_f32_16x16x32_bf16(ao1, *(const short8*)(wsb + WPROJ + (size_t)(ct * 3 + 1) * 512 + lane * 8), acc, 0, 0, 0);
        acc = __builtin_amdgcn_mfma_f32_16x16x32_bf16(ao2, *(const short8*)(wsb + WPROJ + (size_t)(ct * 3 + 2) * 512 + lane * 8), acc, 0, 0, 0);
        float pb = proj_b[ct * 16 + l15];
        #pragma unroll
        for (int r = 0; r < 4; ++r) xrv[ct][r] += acc[r] + pb;
    }

    // ---- LN2 in-register ----
    {
        float gn[6], bn[6];
        #pragma unroll
        for (int ct = 0; ct < 6; ++ct) { gn[ct] = n2g[ct * 16 + l15]; bn[ct] = n2b[ct * 16 + l15]; }
        #pragma unroll
        for (int r = 0; r < 4; ++r) {
            float s = 0.f, q = 0.f;
            #pragma unroll
            for (int ct = 0; ct < 6; ++ct) { s += xrv[ct][r]; q += xrv[ct][r] * xrv[ct][r]; }
            #pragma unroll
            for (int o = 1; o < 16; o <<= 1) { s += __shfl_xor(s, o); q += __shfl_xor(q, o); }
            float mean = s * (1.f / 96.f);
            float var  = q * (1.f / 96.f) - mean * mean;
            float rstd = rsqrtf(var + 1e-5f);
            #pragma unroll
            for (int ct = 0; ct < 6; ++ct)
                xa[m0 + quad * 4 + r][ct * 16 + l15] =
                    f2bf((xrv[ct][r] - mean) * rstd * gn[ct] + bn[ct]);
        }
    }

    // ---- MLP: fc1+GELU double-buffered 32-wide chunks, fc2 accumulate ----
    short8 axn[3];
    #pragma unroll
    for (int kt = 0; kt < 3; ++kt) axn[kt] = *(const short8*)&xa[m0 + l15][kt * 32 + quad * 8];

    ushort* actbase = (ushort*)ps + m0 * 88;       // per-wave 2816 B region
    auto fc1_chunk = [&](int hcc, ushort* buf) {
        #pragma unroll
        for (int c2t = 0; c2t < 2; ++c2t) {
            floatx4 acc = {0.f, 0.f, 0.f, 0.f};
            #pragma unroll
            for (int kt = 0; kt < 3; ++kt) {
                short8 bw = *(const short8*)(wsb + WFC1 + (size_t)((hcc * 2 + c2t) * 3 + kt) * 512 + lane * 8);
                acc = __builtin_amdgcn_mfma_f32_16x16x32_bf16(axn[kt], bw, acc, 0, 0, 0);
            }
            float b1 = fc1_b[(hcc * 2 + c2t) * 16 + l15];
            #pragma unroll
            for (int r = 0; r < 4; ++r)
                buf[(quad * 4 + r) * 44 + c2t * 16 + l15] = f2bf(fgelu(acc[r] + b1));
        }
    };

    floatx4 o2[6];
    #pragma unroll
    for (int ct = 0; ct < 6; ++ct) o2[ct] = (floatx4){0.f, 0.f, 0.f, 0.f};

    fc1_chunk(0, actbase);
    for (int hc = 0; hc < 12; ++hc) {
        ushort* cur = actbase + (hc & 1) * 704;
        short8 aact = *(const short8*)(cur + l15 * 44 + quad * 8);
        if (hc < 11) fc1_chunk(hc + 1, actbase + ((hc + 1) & 1) * 704);
        #pragma unroll
        for (int ct = 0; ct < 6; ++ct) {
            short8 bw = *(const short8*)(wsb + WFC2 + (size_t)(ct * 12 + hc) * 512 + lane * 8);
            o2[ct] = __builtin_amdgcn_mfma_f32_16x16x32_bf16(aact, bw, o2[ct], 0, 0, 0);
        }
    }

    // ---- final: out = xr + fc2 + bias (xr held in registers) ----
    #pragma unroll
    for (int ct = 0; ct < 6; ++ct) {
        float b2 = fc2_b[ct * 16 + l15];
        #pragma unroll
        for (int r = 0; r < 4; ++r)
            if (vld[r]) out[gib[r] + ct * 16 + l15] = xrv[ct][r] + o2[ct][r] + b2;
    }
}

// ---------------------------------------------------------------------------
extern "C" void kernel_launch(void* const* d_in, const int* in_sizes, int n_in,
                              void* d_out, int out_size, void* d_ws, size_t ws_size,
                              hipStream_t stream) {
    const float* x      = (const float*)d_in[0];
    const float* n1g    = (const float*)d_in[1];
    const float* n1b    = (const float*)d_in[2];
    const float* qkv_w  = (const float*)d_in[3];
    const float* qkv_b  = (const float*)d_in[4];
    const float* rpb    = (const float*)d_in[5];
    const float* proj_w = (const float*)d_in[6];
    const float* proj_b = (const float*)d_in[7];
    const float* n2g    = (const float*)d_in[8];
    const float* n2b    = (const float*)d_in[9];
    const float* fc1_w  = (const float*)d_in[10];
    const float* fc1_b  = (const float*)d_in[11];
    const float* fc2_w  = (const float*)d_in[12];
    const float* fc2_b  = (const float*)d_in[13];
    float* out = (float*)d_out;
    ushort* wsb = (ushort*)d_ws;

    wconv<<<NFRAG / 4, 256, 0, stream>>>(qkv_w, proj_w, fc1_w, fc2_w, wsb);
    swin_kernel<<<BB * 64, 256, 0, stream>>>(
        x, n1g, n1b, wsb, qkv_b, rpb, proj_b, n2g, n2b, fc1_b, fc2_b, out);
}